// Round 15
// baseline (171.962 us; speedup 1.0000x reference)
//
#include <hip/hip_runtime.h>

#define N_NODES 100000
#define N_EDGES 3200000
#define IN_FEAT 512
#define HID 16
#define BNODES 128                        // nodes per bucket (dst >> 7)
#define NB 782                            // ceil(100000/128)
#define CHUNK 8192
#define NCHUNKS ((N_EDGES + CHUNK - 1) / CHUNK)   // 391
#define G1_ROWS 64
#define G1_STR4 33                        // LDS row stride in float4 (132 floats)
#define G1_GRID ((N_NODES + 1 + G1_ROWS - 1) / G1_ROWS)  // 1563, covers sentinel

typedef float f32x4 __attribute__((ext_vector_type(4)));

// ---- init: edge dtype probe + ghist zero -----------------------------------
__global__ __launch_bounds__(1024)
void k_init(const void* ei, int* flag, int* ghist) {
    int tid = threadIdx.x;
    if (tid < 64) {                          // wave 0, all lanes active
        const int* p = (const int*)ei;
        bool nz = (p[2 * tid + 1] != 0);
        unsigned long long m = __ballot(nz);
        if (tid == 0) *flag = (m == 0ull) ? 1 : 0;   // 1 => int64 storage
    }
    for (int i = tid; i < NB; i += 1024) ghist[i] = 0;
}

__device__ __forceinline__ int load_dst(const void* ei, int is64, int e) {
    if (is64) return (int)((const long long*)ei)[(long long)N_EDGES + e];
    return ((const int*)ei)[N_EDGES + e];
}
__device__ __forceinline__ int load_src(const void* ei, int is64, int e) {
    if (is64) return (int)((const long long*)ei)[e];
    return ((const int*)ei)[e];
}

// ---- bucket histogram (int atomics: native) --------------------------------
__global__ void k_hist(const void* ei, const int* __restrict__ flag,
                       int* __restrict__ ghist) {
    __shared__ int h[NB];
    int tid = threadIdx.x;
    int is64 = *flag;
    for (int i = tid; i < NB; i += 256) h[i] = 0;
    __syncthreads();
    for (int e = blockIdx.x * 256 + tid; e < N_EDGES; e += gridDim.x * 256)
        atomicAdd(&h[load_dst(ei, is64, e) >> 7], 1);
    __syncthreads();
    for (int i = tid; i < NB; i += 256)
        if (h[i]) atomicAdd(&ghist[i], h[i]);
}

// ---- exclusive scan over NB buckets (one block) ----------------------------
__global__ __launch_bounds__(1024)
void k_scan(const int* __restrict__ ghist, int* __restrict__ goff,
            int* __restrict__ gcursor) {
    __shared__ int s[1024];
    int tid = threadIdx.x;
    int v = (tid < NB) ? ghist[tid] : 0;
    s[tid] = v;
    __syncthreads();
    for (int o = 1; o < 1024; o <<= 1) {
        int t = (tid >= o) ? s[tid - o] : 0;
        __syncthreads();
        s[tid] += t;
        __syncthreads();
    }
    int excl = s[tid] - v;                 // tid==NB -> total (v==0 there)
    if (tid <= NB) goff[tid] = excl;
    if (tid < NB) gcursor[tid] = excl;
}

// ---- per-chunk LDS counting sort + coalesced bucketed scatter --------------
// entry = src<<7 | (dst & 127); bucket = dst>>7
// bsh[] records each sorted slot's bucket id -> no binary search on writeout.
__global__ __launch_bounds__(1024)
void k_sortscatter(const void* ei, const int* __restrict__ flag,
                   int* __restrict__ gcursor, unsigned* __restrict__ colp) {
    __shared__ unsigned sorted[CHUNK];     // 32 KB
    __shared__ short bsh[CHUNK];           // 16 KB: bucket id per sorted slot
    __shared__ int hist[1024];             // doubles as cursor
    __shared__ int scanL[1024];
    __shared__ int gbase[1024];
    int tid = threadIdx.x;
    int base = blockIdx.x * CHUNK;
    int chunkN = min(CHUNK, N_EDGES - base);
    int is64 = *flag;

    hist[tid] = 0;
    __syncthreads();

    unsigned ent[8];
    short bkt[8];
#pragma unroll
    for (int k = 0; k < 8; ++k) {
        int i = k * 1024 + tid;
        if (i < chunkN) {
            int e = base + i;
            int s = load_src(ei, is64, e);
            int d = load_dst(ei, is64, e);
            int b = d >> 7;
            ent[k] = ((unsigned)s << 7) | (unsigned)(d & 127);
            bkt[k] = (short)b;
            atomicAdd(&hist[b], 1);
        } else bkt[k] = -1;
    }
    __syncthreads();

    int v = hist[tid];
    scanL[tid] = v;
    __syncthreads();
    for (int o = 1; o < 1024; o <<= 1) {
        int t = (tid >= o) ? scanL[tid - o] : 0;
        __syncthreads();
        scanL[tid] += t;
        __syncthreads();
    }
    int excl = scanL[tid] - v;
    __syncthreads();
    scanL[tid] = excl;                     // scanL[NB] == chunkN automatically
    hist[tid] = 0;                         // reuse as within-bucket cursor
    __syncthreads();

#pragma unroll
    for (int k = 0; k < 8; ++k) {
        if (bkt[k] >= 0) {
            int b = bkt[k];
            int pos = atomicAdd(&hist[b], 1);
            int dst = scanL[b] + pos;
            sorted[dst] = ent[k];
            bsh[dst] = bkt[k];
        }
    }
    __syncthreads();

    if (tid < NB) {
        int cnt = scanL[tid + 1] - scanL[tid];
        gbase[tid] = (cnt > 0) ? atomicAdd(&gcursor[tid], cnt) : 0;
    }
    __syncthreads();

    for (int i = tid; i < chunkN; i += 1024) {
        int b = bsh[i];                    // direct lookup (was binary search)
        colp[gbase[b] + (i - scanL[b])] = sorted[i];
    }
}

// ---- per-bucket counting sort by node: colp -> colf (full node CSR) --------
// also emits noff[node], dinv[node]. Only INT LDS atomics (native).
__global__ __launch_bounds__(256)
void k_nodecsr(const int* __restrict__ goff, const unsigned* __restrict__ colp,
               int* __restrict__ noff, int* __restrict__ colf,
               float* __restrict__ dinv) {
    __shared__ int hist[BNODES];
    __shared__ int base[BNODES];
    __shared__ int sc[256];
    int b = blockIdx.x, tid = threadIdx.x;
    if (tid < BNODES) hist[tid] = 0;
    __syncthreads();
    int s0 = goff[b], s1 = goff[b + 1];
    for (int i = s0 + tid; i < s1; i += 256)
        atomicAdd(&hist[colp[i] & 127u], 1);
    __syncthreads();
    int v = (tid < BNODES) ? hist[tid] : 0;
    sc[tid] = v;
    __syncthreads();
    for (int o = 1; o < 256; o <<= 1) {
        int t = (tid >= o) ? sc[tid - o] : 0;
        __syncthreads();
        sc[tid] += t;
        __syncthreads();
    }
    int excl = sc[tid] - v;
    if (tid < BNODES) {
        base[tid] = s0 + excl;
        int node = (b << 7) + tid;
        if (node < N_NODES) {
            noff[node] = s0 + excl;
            dinv[node] = rsqrtf((float)v + 1.0f);   // +1 self-loop
        }
    }
    if (b == NB - 1 && tid == 0) noff[N_NODES] = s1;
    __syncthreads();
    if (tid < BNODES) hist[tid] = 0;       // reuse as cursor
    __syncthreads();
    for (int i = s0 + tid; i < s1; i += 256) {
        unsigned e = colp[i];
        int ld = (int)(e & 127u);
        int pos = atomicAdd(&hist[ld], 1);
        colf[base[ld] + pos] = (int)(e >> 7);
    }
}

// ---- xws = (x @ W1) * dinv : 512B-granular LDS staging, split-K x8 ---------
// 512 thr / 64 rows / chunk 128k; stage wave-instr = 2 rows x 512B contiguous.
// Compute: lane = row, wave w owns k in [128c+16w, +16) -> wave-uniform W1.
// LDS [64][132 floats] = 33.8KB -> 4 blocks/CU = 32 waves/CU.
__global__ __launch_bounds__(512, 4)
void k_gemm1(const float* __restrict__ x, const float* __restrict__ W1,
             const float* __restrict__ dinv, float* __restrict__ xws) {
    __shared__ float lds[G1_ROWS * G1_STR4 * 4];   // 33.8 KB; reused for combine
    int tid = threadIdx.x;
    int l = tid & 63;                      // lane = row within block
    int w = __builtin_amdgcn_readfirstlane(tid >> 6);   // wave id 0..7 (uniform)
    size_t rowbase = (size_t)blockIdx.x * G1_ROWS;
    const float4* xg = (const float4*)x;
    float4* lds4 = (float4*)lds;
    float acc[16];
#pragma unroll
    for (int f = 0; f < 16; ++f) acc[f] = 0.f;

#pragma unroll 1
    for (int c = 0; c < 4; ++c) {
        if (c) __syncthreads();            // previous chunk consumed
        // stage: 64 rows x 32 f4 (128 k) = 2048 f4, 4 per thread;
        // wave-instr = 64 consecutive f4 = 2 rows x 512B contiguous.
        float4 v[4];
#pragma unroll
        for (int i = 0; i < 4; ++i) {
            int li = tid + i * 512;        // 0..2047
            int r = li >> 5, kin = li & 31;
            size_t grow = rowbase + r;
            size_t g4 = (grow < (size_t)N_NODES) ? (grow * 128 + c * 32 + kin)
                                                 : (size_t)(c * 32 + kin);
            v[i] = xg[g4];
        }
#pragma unroll
        for (int i = 0; i < 4; ++i) {
            int li = tid + i * 512;
            int r = li >> 5, kin = li & 31;
            lds4[r * G1_STR4 + kin] = v[i];
        }
        __syncthreads();
        // compute: wave w owns f4-slots [4w, 4w+4) of each row
        const float4* lrow = &lds4[l * G1_STR4 + 4 * w];
#pragma unroll
        for (int kk = 0; kk < 4; ++kk) {
            f32x4 xv = *(const f32x4*)&lrow[kk];
#pragma unroll
            for (int j = 0; j < 4; ++j) {
                const float* wr = W1 + (size_t)(c * 128 + 16 * w + 4 * kk + j) * HID;
#pragma unroll
                for (int f = 0; f < 16; ++f)
                    acc[f] = fmaf(xv[j], wr[f], acc[f]);
            }
        }
    }
    __syncthreads();                       // lds reusable now

    // ---- combine 8-wave split-K partials via LDS [64][132]
    float* red = lds;
#pragma unroll
    for (int f = 0; f < 16; ++f)
        red[l * 132 + w * 16 + f] = acc[f];
    __syncthreads();
    int r = tid >> 3;                      // 0..63
    int fp = (tid & 7) * 2;                // float-pair index
    size_t node = rowbase + r;
    if (node <= (size_t)N_NODES) {         // row N_NODES -> zeros (sentinel)
        float o0 = 0.f, o1 = 0.f;
#pragma unroll
        for (int q = 0; q < 8; ++q) {
            const float* rr = &red[r * 132 + q * 16 + fp];
            o0 += rr[0]; o1 += rr[1];
        }
        float di = (node < (size_t)N_NODES) ? dinv[node] : 0.f;
        *(float2*)(xws + node * HID + fp) = make_float2(o0 * di, o1 * di);
    }
}

// ---- layer-1 aggregation: 16 lanes/node, NO atomics ------------------------
__global__ __launch_bounds__(256)
void k_gather1(const int* __restrict__ noff, const int* __restrict__ colf,
               const float* __restrict__ dinv, const float* __restrict__ xws,
               const float* __restrict__ b1, float* __restrict__ out1) {
    int t = blockIdx.x * 256 + threadIdx.x;   // grid exactly N_NODES*16
    int node = t >> 4;
    int l = t & 15;
    int start = noff[node], end = noff[node + 1];
    const f32x4* xws4 = (const f32x4*)xws;
    float acc[16];
#pragma unroll
    for (int r = 0; r < 16; ++r) acc[r] = 0.f;
    for (int j = start; j < end; j += 16) {
        int jl = j + l;
        int jj = min(jl, end - 1);            // loop guarantees end-1 >= start
        int s = colf[jj];
        s = (jl < end) ? s : N_NODES;         // masked lanes -> zero row
        const f32x4* row = xws4 + (size_t)s * 4;
        f32x4 r0 = row[0], r1 = row[1], r2 = row[2], r3 = row[3];
        acc[0]  += r0.x; acc[1]  += r0.y; acc[2]  += r0.z; acc[3]  += r0.w;
        acc[4]  += r1.x; acc[5]  += r1.y; acc[6]  += r1.z; acc[7]  += r1.w;
        acc[8]  += r2.x; acc[9]  += r2.y; acc[10] += r2.z; acc[11] += r2.w;
        acc[12] += r3.x; acc[13] += r3.y; acc[14] += r3.z; acc[15] += r3.w;
    }
    // butterfly transpose-reduce: after 4 stages lane l holds sum of feature l
    float c8[8];
#pragma unroll
    for (int k = 0; k < 8; ++k) {
        float a0 = acc[2 * k], a1 = acc[2 * k + 1];
        float o0 = __shfl_xor(a0, 1, 16);
        float o1 = __shfl_xor(a1, 1, 16);
        c8[k] = (l & 1) ? (a1 + o1) : (a0 + o0);
    }
    float c4[4];
#pragma unroll
    for (int k = 0; k < 4; ++k) {
        float a0 = c8[2 * k], a1 = c8[2 * k + 1];
        float o0 = __shfl_xor(a0, 2, 16);
        float o1 = __shfl_xor(a1, 2, 16);
        c4[k] = (l & 2) ? (a1 + o1) : (a0 + o0);
    }
    float c2[2];
#pragma unroll
    for (int k = 0; k < 2; ++k) {
        float a0 = c4[2 * k], a1 = c4[2 * k + 1];
        float o0 = __shfl_xor(a0, 4, 16);
        float o1 = __shfl_xor(a1, 4, 16);
        c2[k] = (l & 4) ? (a1 + o1) : (a0 + o0);
    }
    float a0 = c2[0], a1 = c2[1];
    float o0 = __shfl_xor(a0, 8, 16);
    float o1 = __shfl_xor(a1, 8, 16);
    float tot = (l & 8) ? (a1 + o1) : (a0 + o0);

    float self = xws[(size_t)node * HID + l];
    float v = fmaf(dinv[node], tot + self, b1[l]);
    out1[(size_t)node * HID + l] = fmaxf(v, 0.f);
}

// ---- h2s = (out1 @ W2) * dinv ; writes sentinel row N_NODES ---------------
__global__ void k_layer2(const float* __restrict__ out1, const float* __restrict__ W2,
                         const float* __restrict__ dinv, float* __restrict__ h2s) {
    int i = blockIdx.x * blockDim.x + threadIdx.x;
    if (i > N_NODES) return;
    if (i == N_NODES) { ((float2*)h2s)[i] = make_float2(0.f, 0.f); return; }
    const float4* hv = (const float4*)(out1 + (size_t)i * HID);
    float g0 = 0.f, g1 = 0.f;
#pragma unroll
    for (int q = 0; q < 4; ++q) {
        float4 v = hv[q];
        g0 = fmaf(v.x, W2[(4 * q + 0) * 2 + 0], g0);
        g1 = fmaf(v.x, W2[(4 * q + 0) * 2 + 1], g1);
        g0 = fmaf(v.y, W2[(4 * q + 1) * 2 + 0], g0);
        g1 = fmaf(v.y, W2[(4 * q + 1) * 2 + 1], g1);
        g0 = fmaf(v.z, W2[(4 * q + 2) * 2 + 0], g0);
        g1 = fmaf(v.z, W2[(4 * q + 2) * 2 + 1], g1);
        g0 = fmaf(v.w, W2[(4 * q + 3) * 2 + 0], g0);
        g1 = fmaf(v.w, W2[(4 * q + 3) * 2 + 1], g1);
    }
    float di = dinv[i];
    ((float2*)h2s)[i] = make_float2(g0 * di, g1 * di);
}

// ---- layer-2 aggregation + log_softmax: 16 lanes/node, NO atomics ----------
__global__ __launch_bounds__(256)
void k_gather2(const int* __restrict__ noff, const int* __restrict__ colf,
               const float* __restrict__ dinv, const float* __restrict__ h2s,
               const float* __restrict__ b2, float* __restrict__ y) {
    int t = blockIdx.x * 256 + threadIdx.x;
    int node = t >> 4;
    int l = t & 15;
    int start = noff[node], end = noff[node + 1];
    const float2* h2v = (const float2*)h2s;
    float g0 = 0.f, g1 = 0.f;
    for (int j = start; j < end; j += 16) {
        int jl = j + l;
        int jj = min(jl, end - 1);
        int s = colf[jj];
        s = (jl < end) ? s : N_NODES;
        float2 hv = h2v[s];
        g0 += hv.x; g1 += hv.y;
    }
#pragma unroll
    for (int d = 1; d < 16; d <<= 1) {
        g0 += __shfl_xor(g0, d, 16);
        g1 += __shfl_xor(g1, d, 16);
    }
    if (l == 0) {
        float2 self = h2v[node];
        float di = dinv[node];
        float v0 = fmaf(di, g0 + self.x, b2[0]);
        float v1 = fmaf(di, g1 + self.y, b2[1]);
        float m = fmaxf(v0, v1);
        float lse = m + logf(expf(v0 - m) + expf(v1 - m));
        ((float2*)y)[node] = make_float2(v0 - lse, v1 - lse);
    }
}

extern "C" void kernel_launch(void* const* d_in, const int* in_sizes, int n_in,
                              void* d_out, int out_size, void* d_ws, size_t ws_size,
                              hipStream_t stream) {
    const float* x  = (const float*)d_in[0];
    const void*  ei = d_in[1];
    const float* W1 = (const float*)d_in[2];
    const float* b1 = (const float*)d_in[3];
    const float* W2 = (const float*)d_in[4];
    const float* b2 = (const float*)d_in[5];
    float* y = (float*)d_out;

    char* w = (char*)d_ws;
    int*      flag    = (int*)(w + 0);
    int*      ghist   = (int*)(w + 1024);        // NB ints
    int*      goff    = (int*)(w + 8192);        // NB+1 ints
    int*      gcursor = (int*)(w + 16384);       // NB ints
    float*    dinv    = (float*)(w + 24576);     // 400 KB
    int*      noff    = (int*)(w + 425984);      // (N+1) ints
    unsigned* colp    = (unsigned*)(w + 828416); // 12.8 MB (dead after nodecsr)
    float*    xws     = (float*)(w + 828416);    // ALIAS over colp; (N+1)x16 f32
    float*    out1    = (float*)(w + 7228480);   // 6.4 MB (still inside colp+gap)
    int*      colf    = (int*)(w + 13631488);    // 12.8 MB
    float*    h2s     = (float*)(w + 26433536);  // (N+1)x2 f32
    // total ws use: ~27.3 MB

    k_init<<<1, 1024, 0, stream>>>(ei, flag, ghist);
    k_hist<<<512, 256, 0, stream>>>(ei, flag, ghist);
    k_scan<<<1, 1024, 0, stream>>>(ghist, goff, gcursor);
    k_sortscatter<<<NCHUNKS, 1024, 0, stream>>>(ei, flag, gcursor, colp);
    k_nodecsr<<<NB, 256, 0, stream>>>(goff, colp, noff, colf, dinv);
    // colp is dead from here; xws aliases it (sentinel row written by gemm1).
    k_gemm1<<<G1_GRID, 512, 0, stream>>>(x, W1, dinv, xws);
    k_gather1<<<(N_NODES * 16) / 256, 256, 0, stream>>>(noff, colf, dinv, xws, b1, out1);
    k_layer2<<<(N_NODES + 1 + 255) / 256, 256, 0, stream>>>(out1, W2, dinv, h2s);
    k_gather2<<<(N_NODES * 16) / 256, 256, 0, stream>>>(noff, colf, dinv, h2s, b2, y);
}

// Round 16
// 165.696 us; speedup vs baseline: 1.0378x; 1.0378x over previous
//
#include <hip/hip_runtime.h>

#define N_NODES 100000
#define N_EDGES 3200000
#define IN_FEAT 512
#define HID 16
#define BNODES 128                        // nodes per bucket (dst >> 7)
#define NB 782                            // ceil(100000/128)
#define BCAP 6144                         // fixed bucket capacity (E=4092, sigma~64)
#define CHUNK 8192
#define NCHUNKS ((N_EDGES + CHUNK - 1) / CHUNK)   // 391
#define G1_ROWS 64
#define G1_STRIDE 68                      // floats; 272B row pitch (16B aligned)
#define G1_GRID ((N_NODES + 1 + G1_ROWS - 1) / G1_ROWS)  // 1563, covers sentinel

typedef float f32x4 __attribute__((ext_vector_type(4)));

__device__ __forceinline__ int load_dst(const void* ei, int is64, int e) {
    if (is64) return (int)((const long long*)ei)[(long long)N_EDGES + e];
    return ((const int*)ei)[N_EDGES + e];
}
__device__ __forceinline__ int load_src(const void* ei, int is64, int e) {
    if (is64) return (int)((const long long*)ei)[e];
    return ((const int*)ei)[e];
}

// ---- per-chunk LDS counting sort -> fixed-capacity buckets -----------------
// entry = src<<7 | (dst & 127); bucket = dst>>7; bucket b lives at b*BCAP.
// int64-vs-int32 edge storage detected inline per block (no dependency).
__global__ __launch_bounds__(1024)
void k_sortscatter(const void* ei, int* __restrict__ gcnt,
                   unsigned* __restrict__ colp) {
    __shared__ unsigned sorted[CHUNK];     // 32 KB
    __shared__ short bsh[CHUNK];           // 16 KB: bucket id per sorted slot
    __shared__ int hist[1024];             // doubles as cursor
    __shared__ int scanL[1024];
    __shared__ int gbase[1024];
    __shared__ int sflag;
    int tid = threadIdx.x;
    int base = blockIdx.x * CHUNK;
    int chunkN = min(CHUNK, N_EDGES - base);

    if (tid < 64) {                        // wave 0: probe storage width
        const int* p = (const int*)ei;
        bool nz = (p[2 * tid + 1] != 0);
        unsigned long long m = __ballot(nz);
        if (tid == 0) sflag = (m == 0ull) ? 1 : 0;   // 1 => int64 storage
    }
    hist[tid] = 0;
    __syncthreads();
    int is64 = sflag;

    unsigned ent[8];
    short bkt[8];
#pragma unroll
    for (int k = 0; k < 8; ++k) {
        int i = k * 1024 + tid;
        if (i < chunkN) {
            int e = base + i;
            int s = load_src(ei, is64, e);
            int d = load_dst(ei, is64, e);
            int b = d >> 7;
            ent[k] = ((unsigned)s << 7) | (unsigned)(d & 127);
            bkt[k] = (short)b;
            atomicAdd(&hist[b], 1);
        } else bkt[k] = -1;
    }
    __syncthreads();

    int v = hist[tid];
    scanL[tid] = v;
    __syncthreads();
    for (int o = 1; o < 1024; o <<= 1) {
        int t = (tid >= o) ? scanL[tid - o] : 0;
        __syncthreads();
        scanL[tid] += t;
        __syncthreads();
    }
    int excl = scanL[tid] - v;
    __syncthreads();
    scanL[tid] = excl;                     // scanL[NB] == chunkN automatically
    hist[tid] = 0;                         // reuse as within-bucket cursor
    __syncthreads();

#pragma unroll
    for (int k = 0; k < 8; ++k) {
        if (bkt[k] >= 0) {
            int b = bkt[k];
            int pos = atomicAdd(&hist[b], 1);
            int dst = scanL[b] + pos;
            sorted[dst] = ent[k];
            bsh[dst] = bkt[k];
        }
    }
    __syncthreads();

    if (tid < NB) {
        int cnt = scanL[tid + 1] - scanL[tid];
        gbase[tid] = tid * BCAP + ((cnt > 0) ? atomicAdd(&gcnt[tid], cnt) : 0);
    }
    __syncthreads();

    for (int i = tid; i < chunkN; i += 1024) {
        int b = bsh[i];                    // direct lookup
        colp[gbase[b] + (i - scanL[b])] = sorted[i];
    }
}

// ---- FUSED: blocks [0,NB) build node-CSR; blocks [NB, NB+G1_GRID) do gemm --
// CSR path: counting sort by local node; emits noff/ndeg/dinv/colf.
// gemm path: xw = x @ W1 RAW (no dinv; dinv applied at gather). R14 config:
// 17.4 KB LDS, 8 chunks of 64k, b128 staging, wave-uniform W1 (SGPR).
__global__ __launch_bounds__(256, 8)
void k_csr_gemm(const int* __restrict__ gcnt, const unsigned* __restrict__ colp,
                const float* __restrict__ x, const float* __restrict__ W1,
                int* __restrict__ noff, int* __restrict__ ndeg,
                float* __restrict__ dinv, int* __restrict__ colf,
                float* __restrict__ xw) {
    __shared__ float smem[G1_ROWS * G1_STRIDE];   // 17.4 KB (union)
    int tid = threadIdx.x;

    if (blockIdx.x < NB) {
        // ---------------- node-CSR build (one bucket per block) -------------
        int* hist = (int*)smem;            // [128]
        int* bse  = hist + BNODES;         // [128]
        int* sc   = bse + BNODES;          // [256]
        int b = blockIdx.x;
        if (tid < BNODES) hist[tid] = 0;
        __syncthreads();
        int s0 = b * BCAP, s1 = s0 + gcnt[b];
        for (int i = s0 + tid; i < s1; i += 256)
            atomicAdd(&hist[colp[i] & 127u], 1);
        __syncthreads();
        int v = (tid < BNODES) ? hist[tid] : 0;
        sc[tid] = v;
        __syncthreads();
        for (int o = 1; o < 256; o <<= 1) {
            int t = (tid >= o) ? sc[tid - o] : 0;
            __syncthreads();
            sc[tid] += t;
            __syncthreads();
        }
        int excl = sc[tid] - v;
        if (tid < BNODES) {
            bse[tid] = s0 + excl;
            int node = (b << 7) + tid;
            if (node < N_NODES) {
                noff[node] = s0 + excl;
                ndeg[node] = v;
                dinv[node] = rsqrtf((float)v + 1.0f);   // +1 self-loop
            }
        }
        __syncthreads();
        if (tid < BNODES) hist[tid] = 0;   // reuse as cursor
        __syncthreads();
        for (int i = s0 + tid; i < s1; i += 256) {
            unsigned e = colp[i];
            int ld = (int)(e & 127u);
            int pos = atomicAdd(&hist[ld], 1);
            colf[bse[ld] + pos] = (int)(e >> 7);
        }
        return;
    }

    // ---------------- gemm: xw = x @ W1 (raw) ---------------------------
    int l = tid & 63;                      // lane = row within block
    int w = __builtin_amdgcn_readfirstlane(tid >> 6);   // wave id (uniform)
    size_t rowbase = (size_t)(blockIdx.x - NB) * G1_ROWS;
    const float4* xg = (const float4*)x;
    float acc[16];
#pragma unroll
    for (int f = 0; f < 16; ++f) acc[f] = 0.f;

#pragma unroll 1
    for (int c = 0; c < 8; ++c) {
        if (c) __syncthreads();            // previous chunk consumed
#pragma unroll
        for (int i = 0; i < 4; ++i) {
            int li = tid + i * 256;        // 0..1023
            int r = li >> 4, kin = li & 15;
            size_t grow = rowbase + r;
            size_t g4 = (grow < (size_t)N_NODES) ? (grow * 128 + c * 16 + kin)
                                                 : (size_t)(c * 16 + kin);
            float4 v = xg[g4];
            *(float4*)&smem[r * G1_STRIDE + 4 * kin] = v;
        }
        __syncthreads();
        const float* lrow = &smem[l * G1_STRIDE + 16 * w];
#pragma unroll
        for (int kk = 0; kk < 4; ++kk) {
            f32x4 xv = *(const f32x4*)(lrow + 4 * kk);
#pragma unroll
            for (int j = 0; j < 4; ++j) {
                const float* wr = W1 + (size_t)(c * 64 + 16 * w + 4 * kk + j) * HID;
#pragma unroll
                for (int f = 0; f < 16; ++f)
                    acc[f] = fmaf(xv[j], wr[f], acc[f]);
            }
        }
    }
    __syncthreads();                       // smem reusable now

    float* red = smem;                     // [64][68]
#pragma unroll
    for (int f = 0; f < 16; ++f)
        red[l * 68 + w * 16 + f] = acc[f];
    __syncthreads();
    int r = tid >> 2;                      // 0..63
    int fg = (tid & 3) * 4;
    size_t node = rowbase + r;
    if (node <= (size_t)N_NODES) {         // row N_NODES -> zeros (sentinel)
        float o0 = 0.f, o1 = 0.f, o2 = 0.f, o3 = 0.f;
#pragma unroll
        for (int qq = 0; qq < 4; ++qq) {
            const float* rr = &red[r * 68 + qq * 16 + fg];
            o0 += rr[0]; o1 += rr[1]; o2 += rr[2]; o3 += rr[3];
        }
        float4 out = (node < (size_t)N_NODES)
                     ? make_float4(o0, o1, o2, o3)
                     : make_float4(0.f, 0.f, 0.f, 0.f);
        *(float4*)(xw + node * HID + fg) = out;
    }
}

// ---- layer-1 aggregation: 16 lanes/node; dinv[s] applied in the fma --------
__global__ __launch_bounds__(256)
void k_gather1(const int* __restrict__ noff, const int* __restrict__ ndeg,
               const int* __restrict__ colf, const float* __restrict__ dinv,
               const float* __restrict__ xw, const float* __restrict__ b1,
               float* __restrict__ out1) {
    int t = blockIdx.x * 256 + threadIdx.x;   // grid exactly N_NODES*16
    int node = t >> 4;
    int l = t & 15;
    int start = noff[node];
    int end = start + ndeg[node];
    const f32x4* xw4 = (const f32x4*)xw;
    float acc[16];
#pragma unroll
    for (int r = 0; r < 16; ++r) acc[r] = 0.f;
    for (int j = start; j < end; j += 16) {
        int jl = j + l;
        int jj = min(jl, end - 1);            // loop entered => end-1 >= start
        int s = colf[jj];
        float ds = (jl < end) ? dinv[s] : 0.f;   // masked lanes contribute 0
        const f32x4* row = xw4 + (size_t)s * 4;
        f32x4 r0 = row[0], r1 = row[1], r2 = row[2], r3 = row[3];
        acc[0]  = fmaf(ds, r0.x, acc[0]);  acc[1]  = fmaf(ds, r0.y, acc[1]);
        acc[2]  = fmaf(ds, r0.z, acc[2]);  acc[3]  = fmaf(ds, r0.w, acc[3]);
        acc[4]  = fmaf(ds, r1.x, acc[4]);  acc[5]  = fmaf(ds, r1.y, acc[5]);
        acc[6]  = fmaf(ds, r1.z, acc[6]);  acc[7]  = fmaf(ds, r1.w, acc[7]);
        acc[8]  = fmaf(ds, r2.x, acc[8]);  acc[9]  = fmaf(ds, r2.y, acc[9]);
        acc[10] = fmaf(ds, r2.z, acc[10]); acc[11] = fmaf(ds, r2.w, acc[11]);
        acc[12] = fmaf(ds, r3.x, acc[12]); acc[13] = fmaf(ds, r3.y, acc[13]);
        acc[14] = fmaf(ds, r3.z, acc[14]); acc[15] = fmaf(ds, r3.w, acc[15]);
    }
    // butterfly transpose-reduce: after 4 stages lane l holds sum of feature l
    float c8[8];
#pragma unroll
    for (int k = 0; k < 8; ++k) {
        float a0 = acc[2 * k], a1 = acc[2 * k + 1];
        float o0 = __shfl_xor(a0, 1, 16);
        float o1 = __shfl_xor(a1, 1, 16);
        c8[k] = (l & 1) ? (a1 + o1) : (a0 + o0);
    }
    float c4[4];
#pragma unroll
    for (int k = 0; k < 4; ++k) {
        float a0 = c8[2 * k], a1 = c8[2 * k + 1];
        float o0 = __shfl_xor(a0, 2, 16);
        float o1 = __shfl_xor(a1, 2, 16);
        c4[k] = (l & 2) ? (a1 + o1) : (a0 + o0);
    }
    float c2[2];
#pragma unroll
    for (int k = 0; k < 2; ++k) {
        float a0 = c2 ? 0.f : 0.f, a1 = 0.f;   // placeholder (overwritten)
        a0 = c4[2 * k]; a1 = c4[2 * k + 1];
        float o0 = __shfl_xor(a0, 4, 16);
        float o1 = __shfl_xor(a1, 4, 16);
        c2[k] = (l & 4) ? (a1 + o1) : (a0 + o0);
    }
    float a0 = c2[0], a1 = c2[1];
    float o0 = __shfl_xor(a0, 8, 16);
    float o1 = __shfl_xor(a1, 8, 16);
    float tot = (l & 8) ? (a1 + o1) : (a0 + o0);

    float dd = dinv[node];
    float selfr = xw[(size_t)node * HID + l];          // raw xw
    float vv = fmaf(dd, tot + dd * selfr, b1[l]);      // b + dd*tot + dd^2*self
    out1[(size_t)t] = fmaxf(vv, 0.f);
}

// ---- h2s = (out1 @ W2) * dinv ; writes sentinel row N_NODES ---------------
__global__ void k_layer2(const float* __restrict__ out1, const float* __restrict__ W2,
                         const float* __restrict__ dinv, float* __restrict__ h2s) {
    int i = blockIdx.x * blockDim.x + threadIdx.x;
    if (i > N_NODES) return;
    if (i == N_NODES) { ((float2*)h2s)[i] = make_float2(0.f, 0.f); return; }
    const float4* hv = (const float4*)(out1 + (size_t)i * HID);
    float g0 = 0.f, g1 = 0.f;
#pragma unroll
    for (int q = 0; q < 4; ++q) {
        float4 v = hv[q];
        g0 = fmaf(v.x, W2[(4 * q + 0) * 2 + 0], g0);
        g1 = fmaf(v.x, W2[(4 * q + 0) * 2 + 1], g1);
        g0 = fmaf(v.y, W2[(4 * q + 1) * 2 + 0], g0);
        g1 = fmaf(v.y, W2[(4 * q + 1) * 2 + 1], g1);
        g0 = fmaf(v.z, W2[(4 * q + 2) * 2 + 0], g0);
        g1 = fmaf(v.z, W2[(4 * q + 2) * 2 + 1], g1);
        g0 = fmaf(v.w, W2[(4 * q + 3) * 2 + 0], g0);
        g1 = fmaf(v.w, W2[(4 * q + 3) * 2 + 1], g1);
    }
    float di = dinv[i];
    ((float2*)h2s)[i] = make_float2(g0 * di, g1 * di);
}

// ---- layer-2 aggregation + log_softmax: 16 lanes/node ----------------------
__global__ __launch_bounds__(256)
void k_gather2(const int* __restrict__ noff, const int* __restrict__ ndeg,
               const int* __restrict__ colf, const float* __restrict__ dinv,
               const float* __restrict__ h2s, const float* __restrict__ b2,
               float* __restrict__ y) {
    int t = blockIdx.x * 256 + threadIdx.x;
    int node = t >> 4;
    int l = t & 15;
    int start = noff[node];
    int end = start + ndeg[node];
    const float2* h2v = (const float2*)h2s;
    float g0 = 0.f, g1 = 0.f;
    for (int j = start; j < end; j += 16) {
        int jl = j + l;
        int jj = min(jl, end - 1);
        int s = colf[jj];
        s = (jl < end) ? s : N_NODES;      // sentinel row = zeros
        float2 hv = h2v[s];
        g0 += hv.x; g1 += hv.y;
    }
#pragma unroll
    for (int d = 1; d < 16; d <<= 1) {
        g0 += __shfl_xor(g0, d, 16);
        g1 += __shfl_xor(g1, d, 16);
    }
    if (l == 0) {
        float2 self = h2v[node];
        float di = dinv[node];
        float v0 = fmaf(di, g0 + self.x, b2[0]);
        float v1 = fmaf(di, g1 + self.y, b2[1]);
        float m = fmaxf(v0, v1);
        float lse = m + logf(expf(v0 - m) + expf(v1 - m));
        ((float2*)y)[node] = make_float2(v0 - lse, v1 - lse);
    }
}

extern "C" void kernel_launch(void* const* d_in, const int* in_sizes, int n_in,
                              void* d_out, int out_size, void* d_ws, size_t ws_size,
                              hipStream_t stream) {
    const float* x  = (const float*)d_in[0];
    const void*  ei = d_in[1];
    const float* W1 = (const float*)d_in[2];
    const float* b1 = (const float*)d_in[3];
    const float* W2 = (const float*)d_in[4];
    const float* b2 = (const float*)d_in[5];
    float* y = (float*)d_out;

    char* w = (char*)d_ws;
    int*      gcnt = (int*)(w + 0);               // NB ints
    float*    dinv = (float*)(w + 4096);          // 400 KB
    int*      noff = (int*)(w + 413696);          // 400 KB
    int*      ndeg = (int*)(w + 823296);          // 400 KB
    unsigned* colp = (unsigned*)(w + 1232896);    // NB*BCAP*4 = 19.2 MB
    int*      colf = (int*)(w + 20451328);        // 19.2 MB
    float*    xw   = (float*)(w + 39669760);      // (N+1)*16 f32
    float*    out1 = (float*)(w + 46069824);      // 6.4 MB
    float*    h2s  = (float*)(w + 52469888);      // (N+1)*2 f32
    // total ws use: ~53.3 MB

    hipMemsetAsync(gcnt, 0, NB * sizeof(int), stream);
    k_sortscatter<<<NCHUNKS, 1024, 0, stream>>>(ei, gcnt, colp);
    k_csr_gemm<<<NB + G1_GRID, 256, 0, stream>>>(gcnt, colp, x, W1,
                                                 noff, ndeg, dinv, colf, xw);
    k_gather1<<<(N_NODES * 16) / 256, 256, 0, stream>>>(noff, ndeg, colf, dinv,
                                                        xw, b1, out1);
    k_layer2<<<(N_NODES + 1 + 255) / 256, 256, 0, stream>>>(out1, W2, dinv, h2s);
    k_gather2<<<(N_NODES * 16) / 256, 256, 0, stream>>>(noff, ndeg, colf, dinv,
                                                        h2s, b2, y);
}

// Round 17
// 153.815 us; speedup vs baseline: 1.1180x; 1.0772x over previous
//
#include <hip/hip_runtime.h>

#define N_NODES 100000
#define N_EDGES 3200000
#define IN_FEAT 512
#define HID 16
#define BNODES 128                        // nodes per bucket (dst >> 7)
#define NB 782                            // ceil(100000/128)
#define BCAP 6144                         // fixed bucket capacity (E=4092, sigma~64)
#define CHUNK 8192
#define NCHUNKS ((N_EDGES + CHUNK - 1) / CHUNK)   // 391
#define G1_ROWS 64
#define G1_GRID ((N_NODES + 1 + G1_ROWS - 1) / G1_ROWS)  // 1563, covers sentinel

typedef float f32x4 __attribute__((ext_vector_type(4)));

__device__ __forceinline__ int load_dst(const void* ei, int is64, int e) {
    if (is64) return (int)((const long long*)ei)[(long long)N_EDGES + e];
    return ((const int*)ei)[N_EDGES + e];
}
__device__ __forceinline__ int load_src(const void* ei, int is64, int e) {
    if (is64) return (int)((const long long*)ei)[e];
    return ((const int*)ei)[e];
}

// ---- per-chunk LDS counting sort -> fixed-capacity buckets -----------------
__global__ __launch_bounds__(1024)
void k_sortscatter(const void* ei, int* __restrict__ gcnt,
                   unsigned* __restrict__ colp) {
    __shared__ unsigned sorted[CHUNK];     // 32 KB
    __shared__ short bsh[CHUNK];           // 16 KB
    __shared__ int hist[1024];
    __shared__ int scanL[1024];
    __shared__ int gbase[1024];
    __shared__ int sflag;
    int tid = threadIdx.x;
    int base = blockIdx.x * CHUNK;
    int chunkN = min(CHUNK, N_EDGES - base);

    if (tid < 64) {                        // wave 0: probe storage width
        const int* p = (const int*)ei;
        bool nz = (p[2 * tid + 1] != 0);
        unsigned long long m = __ballot(nz);
        if (tid == 0) sflag = (m == 0ull) ? 1 : 0;   // 1 => int64 storage
    }
    hist[tid] = 0;
    __syncthreads();
    int is64 = sflag;

    unsigned ent[8];
    short bkt[8];
#pragma unroll
    for (int k = 0; k < 8; ++k) {
        int i = k * 1024 + tid;
        if (i < chunkN) {
            int e = base + i;
            int s = load_src(ei, is64, e);
            int d = load_dst(ei, is64, e);
            int b = d >> 7;
            ent[k] = ((unsigned)s << 7) | (unsigned)(d & 127);
            bkt[k] = (short)b;
            atomicAdd(&hist[b], 1);
        } else bkt[k] = -1;
    }
    __syncthreads();

    int v = hist[tid];
    scanL[tid] = v;
    __syncthreads();
    for (int o = 1; o < 1024; o <<= 1) {
        int t = (tid >= o) ? scanL[tid - o] : 0;
        __syncthreads();
        scanL[tid] += t;
        __syncthreads();
    }
    int excl = scanL[tid] - v;
    __syncthreads();
    scanL[tid] = excl;
    hist[tid] = 0;
    __syncthreads();

#pragma unroll
    for (int k = 0; k < 8; ++k) {
        if (bkt[k] >= 0) {
            int b = bkt[k];
            int pos = atomicAdd(&hist[b], 1);
            int dst = scanL[b] + pos;
            sorted[dst] = ent[k];
            bsh[dst] = bkt[k];
        }
    }
    __syncthreads();

    if (tid < NB) {
        int cnt = scanL[tid + 1] - scanL[tid];
        gbase[tid] = tid * BCAP + ((cnt > 0) ? atomicAdd(&gcnt[tid], cnt) : 0);
    }
    __syncthreads();

    for (int i = tid; i < chunkN; i += 1024) {
        int b = bsh[i];
        colp[gbase[b] + (i - scanL[b])] = sorted[i];
    }
}

// ---- FUSED: blocks [0,NB) build node-CSR; blocks [NB,NB+G1_GRID) do gemm ---
// gemm: xw = x @ W1 raw (dinv applied at gather). Staging via
// global_load_lds dwordx4 (async DMA, linear LDS dest, pre-swizzled source
// f4 ^= row&15 for conflict-free reads), double-buffered: chunk c+1's DMA
// issued BEFORE chunk c's compute; one vmcnt(0)+barrier per chunk.
__global__ __launch_bounds__(256, 8)
void k_csr_gemm(const int* __restrict__ gcnt, const unsigned* __restrict__ colp,
                const float* __restrict__ x, const float* __restrict__ W1,
                int* __restrict__ noff, int* __restrict__ ndeg,
                float* __restrict__ dinv, int* __restrict__ colf,
                float* __restrict__ xw) {
    __shared__ float smemA[G1_ROWS * 68];  // 17.4 KB: buf0 (16KB) + combine
    __shared__ float smemB[G1_ROWS * 64];  // 16 KB: buf1
    int tid = threadIdx.x;

    if (blockIdx.x < NB) {
        // ---------------- node-CSR build (one bucket per block) -------------
        int* hist = (int*)smemA;           // [128]
        int* bse  = hist + BNODES;         // [128]
        int* sc   = bse + BNODES;          // [256]
        int b = blockIdx.x;
        if (tid < BNODES) hist[tid] = 0;
        __syncthreads();
        int s0 = b * BCAP, s1 = s0 + gcnt[b];
        for (int i = s0 + tid; i < s1; i += 256)
            atomicAdd(&hist[colp[i] & 127u], 1);
        __syncthreads();
        int v = (tid < BNODES) ? hist[tid] : 0;
        sc[tid] = v;
        __syncthreads();
        for (int o = 1; o < 256; o <<= 1) {
            int t = (tid >= o) ? sc[tid - o] : 0;
            __syncthreads();
            sc[tid] += t;
            __syncthreads();
        }
        int excl = sc[tid] - v;
        if (tid < BNODES) {
            bse[tid] = s0 + excl;
            int node = (b << 7) + tid;
            if (node < N_NODES) {
                noff[node] = s0 + excl;
                ndeg[node] = v;
                dinv[node] = rsqrtf((float)v + 1.0f);   // +1 self-loop
            }
        }
        __syncthreads();
        if (tid < BNODES) hist[tid] = 0;
        __syncthreads();
        for (int i = s0 + tid; i < s1; i += 256) {
            unsigned e = colp[i];
            int ld = (int)(e & 127u);
            int pos = atomicAdd(&hist[ld], 1);
            colf[bse[ld] + pos] = (int)(e >> 7);
        }
        return;
    }

    // ---------------- gemm path ---------------------------------------------
    int l = tid & 63;                      // lane = row within block
    int w = __builtin_amdgcn_readfirstlane(tid >> 6);   // wave id (uniform)
    int w64 = tid & ~63;                   // wave base within block
    size_t rowbase = (size_t)(blockIdx.x - NB) * G1_ROWS;
    const float4* xg = (const float4*)x;
    float acc[16];
#pragma unroll
    for (int f = 0; f < 16; ++f) acc[f] = 0.f;

    // DMA issue: 4 x global_load_lds_dwordx4; LDS dest linear (li*16B),
    // source f4 pre-swizzled so logical slot j of row r sits at j^(r&15).
#define G1_DMA(DSTBASE, C)                                                    \
    {                                                                         \
        _Pragma("unroll")                                                     \
        for (int i = 0; i < 4; ++i) {                                         \
            int li = tid + i * 256;                                           \
            int r = li >> 4, kin = li & 15;                                   \
            int f4l = kin ^ (r & 15);                                         \
            size_t grow = rowbase + r;                                        \
            size_t g4 = (grow < (size_t)N_NODES)                              \
                        ? (grow * 128 + (C) * 16 + f4l)                       \
                        : (size_t)((C) * 16 + f4l);                           \
            const float4* srcp = xg + g4;                                     \
            float* dstf = (DSTBASE) + (size_t)(w64 + i * 256) * 4;            \
            __builtin_amdgcn_global_load_lds(                                 \
                (const __attribute__((address_space(1))) void*)srcp,          \
                (__attribute__((address_space(3))) void*)dstf, 16, 0, 0);     \
        }                                                                     \
    }

    G1_DMA(smemA, 0);                      // prologue: chunk 0 -> bufA
#pragma unroll 1
    for (int c = 0; c < 8; ++c) {
        asm volatile("s_waitcnt vmcnt(0)" ::: "memory");
        __syncthreads();                   // this chunk's tile is ready
        float* cur = (c & 1) ? smemB : smemA;
        float* nxt = (c & 1) ? smemA : smemB;
        if (c < 7) G1_DMA(nxt, c + 1);     // async: flies during compute
        const float* lbase = cur + l * 64;
#pragma unroll
        for (int kk = 0; kk < 4; ++kk) {
            int phys = (4 * w + kk) ^ (l & 15);
            f32x4 xv = *(const f32x4*)(lbase + phys * 4);
#pragma unroll
            for (int j = 0; j < 4; ++j) {
                const float* wr = W1 + (size_t)(c * 64 + 16 * w + 4 * kk + j) * HID;
#pragma unroll
                for (int f = 0; f < 16; ++f)
                    acc[f] = fmaf(xv[j], wr[f], acc[f]);
            }
        }
    }
#undef G1_DMA
    __syncthreads();                       // smemA reusable now

    // ---- combine 4-wave split-K partials via LDS [64][68]
    float* red = smemA;
#pragma unroll
    for (int f = 0; f < 16; ++f)
        red[l * 68 + w * 16 + f] = acc[f];
    __syncthreads();
    int r = tid >> 2;
    int fg = (tid & 3) * 4;
    size_t node = rowbase + r;
    if (node <= (size_t)N_NODES) {
        float o0 = 0.f, o1 = 0.f, o2 = 0.f, o3 = 0.f;
#pragma unroll
        for (int qq = 0; qq < 4; ++qq) {
            const float* rr = &red[r * 68 + qq * 16 + fg];
            o0 += rr[0]; o1 += rr[1]; o2 += rr[2]; o3 += rr[3];
        }
        float4 out = (node < (size_t)N_NODES)
                     ? make_float4(o0, o1, o2, o3)
                     : make_float4(0.f, 0.f, 0.f, 0.f);
        *(float4*)(xw + node * HID + fg) = out;
    }
}

// ---- layer-1 aggregation + FUSED layer-2: 16 lanes/node, NO atomics --------
// After the butterfly, lane l holds out1 feature l -> two more 16-lane
// reduces produce h2s directly (k_layer2 + out1 array eliminated).
__global__ __launch_bounds__(256)
void k_gather1(const int* __restrict__ noff, const int* __restrict__ ndeg,
               const int* __restrict__ colf, const float* __restrict__ dinv,
               const float* __restrict__ xw, const float* __restrict__ b1,
               const float* __restrict__ W2, float* __restrict__ h2s) {
    int t = blockIdx.x * 256 + threadIdx.x;   // grid exactly N_NODES*16
    int node = t >> 4;
    int l = t & 15;
    int start = noff[node];
    int end = start + ndeg[node];
    const f32x4* xw4 = (const f32x4*)xw;
    float acc[16];
#pragma unroll
    for (int r = 0; r < 16; ++r) acc[r] = 0.f;
    for (int j = start; j < end; j += 16) {
        int jl = j + l;
        int jj = min(jl, end - 1);
        int s = colf[jj];
        float ds = (jl < end) ? dinv[s] : 0.f;   // masked lanes contribute 0
        const f32x4* row = xw4 + (size_t)s * 4;
        f32x4 r0 = row[0], r1 = row[1], r2 = row[2], r3 = row[3];
        acc[0]  = fmaf(ds, r0.x, acc[0]);  acc[1]  = fmaf(ds, r0.y, acc[1]);
        acc[2]  = fmaf(ds, r0.z, acc[2]);  acc[3]  = fmaf(ds, r0.w, acc[3]);
        acc[4]  = fmaf(ds, r1.x, acc[4]);  acc[5]  = fmaf(ds, r1.y, acc[5]);
        acc[6]  = fmaf(ds, r1.z, acc[6]);  acc[7]  = fmaf(ds, r1.w, acc[7]);
        acc[8]  = fmaf(ds, r2.x, acc[8]);  acc[9]  = fmaf(ds, r2.y, acc[9]);
        acc[10] = fmaf(ds, r2.z, acc[10]); acc[11] = fmaf(ds, r2.w, acc[11]);
        acc[12] = fmaf(ds, r3.x, acc[12]); acc[13] = fmaf(ds, r3.y, acc[13]);
        acc[14] = fmaf(ds, r3.z, acc[14]); acc[15] = fmaf(ds, r3.w, acc[15]);
    }
    // butterfly transpose-reduce: lane l ends holding feature l
    float c8[8];
#pragma unroll
    for (int k = 0; k < 8; ++k) {
        float a0 = acc[2 * k], a1 = acc[2 * k + 1];
        float o0 = __shfl_xor(a0, 1, 16);
        float o1 = __shfl_xor(a1, 1, 16);
        c8[k] = (l & 1) ? (a1 + o1) : (a0 + o0);
    }
    float c4[4];
#pragma unroll
    for (int k = 0; k < 4; ++k) {
        float a0 = c8[2 * k], a1 = c8[2 * k + 1];
        float o0 = __shfl_xor(a0, 2, 16);
        float o1 = __shfl_xor(a1, 2, 16);
        c4[k] = (l & 2) ? (a1 + o1) : (a0 + o0);
    }
    float c2[2];
#pragma unroll
    for (int k = 0; k < 2; ++k) {
        float a0 = c4[2 * k], a1 = c4[2 * k + 1];
        float o0 = __shfl_xor(a0, 4, 16);
        float o1 = __shfl_xor(a1, 4, 16);
        c2[k] = (l & 4) ? (a1 + o1) : (a0 + o0);
    }
    float a0 = c2[0], a1 = c2[1];
    float o0 = __shfl_xor(a0, 8, 16);
    float o1 = __shfl_xor(a1, 8, 16);
    float tot = (l & 8) ? (a1 + o1) : (a0 + o0);

    float dd = dinv[node];
    float selfr = xw[(size_t)node * HID + l];          // raw xw
    float vv = fmaf(dd, tot + dd * selfr, b1[l]);      // b + dd*tot + dd^2*self
    float h = fmaxf(vv, 0.f);                          // relu(out1[node][l])

    // fused layer-2: h2s[node] = (out1row @ W2) * dd
    float2 w2 = ((const float2*)W2)[l];
    float g0 = h * w2.x, g1 = h * w2.y;
#pragma unroll
    for (int d = 1; d < 16; d <<= 1) {
        g0 += __shfl_xor(g0, d, 16);
        g1 += __shfl_xor(g1, d, 16);
    }
    if (l == 0)
        ((float2*)h2s)[node] = make_float2(g0 * dd, g1 * dd);
    if (t == 0)
        ((float2*)h2s)[N_NODES] = make_float2(0.f, 0.f);   // sentinel
}

// ---- layer-2 aggregation + log_softmax: 16 lanes/node ----------------------
__global__ __launch_bounds__(256)
void k_gather2(const int* __restrict__ noff, const int* __restrict__ ndeg,
               const int* __restrict__ colf, const float* __restrict__ dinv,
               const float* __restrict__ h2s, const float* __restrict__ b2,
               float* __restrict__ y) {
    int t = blockIdx.x * 256 + threadIdx.x;
    int node = t >> 4;
    int l = t & 15;
    int start = noff[node];
    int end = start + ndeg[node];
    const float2* h2v = (const float2*)h2s;
    float g0 = 0.f, g1 = 0.f;
    for (int j = start; j < end; j += 16) {
        int jl = j + l;
        int jj = min(jl, end - 1);
        int s = colf[jj];
        s = (jl < end) ? s : N_NODES;      // sentinel row = zeros
        float2 hv = h2v[s];
        g0 += hv.x; g1 += hv.y;
    }
#pragma unroll
    for (int d = 1; d < 16; d <<= 1) {
        g0 += __shfl_xor(g0, d, 16);
        g1 += __shfl_xor(g1, d, 16);
    }
    if (l == 0) {
        float2 self = h2v[node];
        float di = dinv[node];
        float v0 = fmaf(di, g0 + self.x, b2[0]);
        float v1 = fmaf(di, g1 + self.y, b2[1]);
        float m = fmaxf(v0, v1);
        float lse = m + logf(expf(v0 - m) + expf(v1 - m));
        ((float2*)y)[node] = make_float2(v0 - lse, v1 - lse);
    }
}

extern "C" void kernel_launch(void* const* d_in, const int* in_sizes, int n_in,
                              void* d_out, int out_size, void* d_ws, size_t ws_size,
                              hipStream_t stream) {
    const float* x  = (const float*)d_in[0];
    const void*  ei = d_in[1];
    const float* W1 = (const float*)d_in[2];
    const float* b1 = (const float*)d_in[3];
    const float* W2 = (const float*)d_in[4];
    const float* b2 = (const float*)d_in[5];
    float* y = (float*)d_out;

    char* w = (char*)d_ws;
    int*      gcnt = (int*)(w + 0);               // NB ints
    float*    dinv = (float*)(w + 4096);          // 400 KB
    int*      noff = (int*)(w + 413696);          // 400 KB
    int*      ndeg = (int*)(w + 823296);          // 400 KB
    unsigned* colp = (unsigned*)(w + 1232896);    // NB*BCAP*4 = 19.2 MB
    int*      colf = (int*)(w + 20451328);        // 19.2 MB
    float*    xw   = (float*)(w + 39669760);      // (N+1)*16 f32
    float*    h2s  = (float*)(w + 46069824);      // (N+1)*2 f32
    // total ws use: ~46.9 MB

    hipMemsetAsync(gcnt, 0, NB * sizeof(int), stream);
    k_sortscatter<<<NCHUNKS, 1024, 0, stream>>>(ei, gcnt, colp);
    k_csr_gemm<<<NB + G1_GRID, 256, 0, stream>>>(gcnt, colp, x, W1,
                                                 noff, ndeg, dinv, colf, xw);
    k_gather1<<<(N_NODES * 16) / 256, 256, 0, stream>>>(noff, ndeg, colf, dinv,
                                                        xw, b1, W2, h2s);
    k_gather2<<<(N_NODES * 16) / 256, 256, 0, stream>>>(noff, ndeg, colf, dinv,
                                                        h2s, b2, y);
}